// Round 12
// baseline (8650.610 us; speedup 1.0000x reference)
//
#include <hip/hip_runtime.h>
#include <stdint.h>

// DBN downbeat Viterbi, single persistent 1024-thread workgroup.
// v4: ONE barrier/frame, role-specialized waves.
//   waves 0-3 (beat b, lane j): banded argmax over lring[t-1] — 48-float
//     aligned window (12x ds_read_b128), stores bestp2 = max + dens_t[dsel]
//     (the FRAME-t head value) into parity-buffered LDS.
//   waves 4-15: update, KF4=32 states/thread, end-aligned blocks. Head value
//     never stored; consumers inject patchv=bestp2[(t-1)&1] (hpp mask at i==1,
//     pred_is_head seam, final injection at kk_head).
//   dens precomputed to ws; 64-slot ring refilled frames [t+31,t+62] per 32.
//   lastv history in 32-slot lring; 1 row per wave flushed every 16 frames.
// Gate: T%4==0, T<=64, NP<=256, S<=32*(768-NP)  (=> NT<=768 for any lengths).
// v2 fallback = round-9 proven kernel. Output: float32 (path+logp). Bit-exact.

#define NB 4
#define KF 15        // v2 fallback
#define KF4 32       // v4 update states/thread
#define AOFF 256     // v4 update thread offset (waves 4..15)
#define BW2 48       // v4 argmax per-lane window
#define QW 16
#define NPMAX 256
#define NEGV -1.0e30f

__device__ __forceinline__ float bf16u_to_f(uint16_t u) {
    union { uint32_t i; float f; } v; v.i = ((uint32_t)u) << 16; return v.f;
}
__device__ __forceinline__ void load_acts(const void* p, int isbf, int t, float& a, float& d) {
    if (isbf) {
        const uint16_t* u = (const uint16_t*)p;
        uint32_t w = *(const uint32_t*)(u + 2 * t);
        a = bf16u_to_f((uint16_t)w); d = bf16u_to_f((uint16_t)(w >> 16));
    } else {
        const float2* f = (const float2*)p;
        float2 v = f[t]; a = v.x; d = v.y;
    }
}

// ============================ v4 kernel ============================
__global__ __launch_bounds__(1024) void dbn_viterbi_v4(
    const void* __restrict__ acts_raw,     // F*2, f32 or bf16 (detected)
    const void* __restrict__ lt_raw,       // NB*T*T, f32 or bf16
    const int*  __restrict__ prev_last,    // NB*T
    const int*  __restrict__ first_states, // NB*T
    float*      __restrict__ out,          // F+1 float32
    float*      __restrict__ ws_lastv,     // F*NP floats
    float*      __restrict__ ws_dens,      // F*4 floats
    int T, int S, int F)
{
    const int tid  = (int)threadIdx.x;
    const int NP   = NB * T;
    const int lane = tid & 63;
    const int wvx  = tid >> 6;

    __shared__ alignas(16) float lring[32 * 256];  // lastv ring [slot][beat<<6|i]
    __shared__ alignas(16) float densr[64 * 4];    // dens ring
    __shared__ float bestp2[2 * 256];              // [parity][g]: head value (max+dens)
    __shared__ float bound2[32];                   // [parity][update-wave]
    __shared__ int   fsld[NPMAX];
    __shared__ int   plds[NPMAX];
    __shared__ int   pref[NPMAX + 1];
    __shared__ float wvs[16];
    __shared__ int   wss[16];
    __shared__ int   flag_s, span_s;

    // ---- dtype detection
    if (tid == 0) {
        const uint16_t* au = (const uint16_t*)acts_raw;
        int bf = 1;
        for (int i = 0; i < 32; i++) {
            uint16_t e = au[2 * i];
            uint8_t h8 = (uint8_t)(e >> 8);
            if (!(e == 0 || (h8 >= 0x20 && h8 < 0x40))) bf = 0;
        }
        flag_s = bf; span_s = 0;
    }
    if (tid < NP) { fsld[tid] = first_states[tid]; plds[tid] = prev_last[tid]; }
    for (int i = tid; i < 32 * 256; i += 1024) lring[i] = NEGV;
    if (tid < 32) bound2[tid] = 0.0f;
    __syncthreads();
    const int isbf = flag_s;
    const int nsb  = S / NB;
    const uint16_t* lt_u = (const uint16_t*)lt_raw;
    const float*    lt_f = (const float*)lt_raw;

    // ---- dens precompute (all frames) into ws_dens
    for (int f = tid; f < F; f += 1024) {
        float ab, ad;
        load_acts(acts_raw, isbf, f, ab, ad);
        float4 r;
        r.x = logf(((1.0f - ab) - ad) / 15.0f);
        r.y = logf(ab);
        r.z = logf(ad);
        r.w = 0.0f;
        *(float4*)&ws_dens[f * 4] = r;
    }
    __threadfence();
    if (tid == 0) {
        int acc = 0;
        for (int g = 0; g < NP; g++) {
            int b = g / T, ib = g - b * T;
            int end = (ib + 1 < T) ? fsld[g + 1] : (b + 1) * nsb;
            int L = end - fsld[g];
            pref[g] = acc; acc += (L + KF4 - 1) / KF4;
        }
        pref[NP] = acc;
    }
    __syncthreads();
    const int NT = pref[NP];
    const float vinit = -logf((float)S);
    const int WQ = NP >> 2, TQ = T >> 2;

    if (tid < AOFF) {
        // ================= ARGMAX WAVES (0..3) =================
        const int b = wvx, j = lane;
        const bool act_a = (j < T);
        const int rowbase = ((b + 3) & 3) << 6;
        const int dsel = (b == 0) ? 2 : 1;
        int c0 = 0, colbase = 0;
        float ltb[BW2];
        #pragma unroll
        for (int u = 0; u < BW2; u++) ltb[u] = NEGV;
        if (act_a) {
            colbase = b * T * T + j;
            int lo = T, hi = 0;
            for (int i = 0; i < T; i++) {
                float v = isbf ? bf16u_to_f(lt_u[colbase + i * T]) : lt_f[colbase + i * T];
                if (v > -1e29f) { if (i < lo) lo = i; if (i > hi) hi = i; }
            }
            if (lo > hi) { lo = 0; hi = 0; }
            atomicMax(&span_s, hi - lo + 1);
            c0 = lo & ~3;
            if (c0 > 64 - BW2) c0 = 64 - BW2;
            for (int u = 0; u < BW2; u++) {
                int i = c0 + u;
                if (i < T) ltb[u] = isbf ? bf16u_to_f(lt_u[colbase + i * T]) : lt_f[colbase + i * T];
            }
        }
        if (tid < 256) bestp2[256 + tid] = vinit;     // parity-1 seed (frame -1)
        if (tid < 64 && tid < F) {
            float4 r = *(const float4*)&ws_dens[tid * 4];
            *(float4*)&densr[tid * 4] = r;
        }
        __syncthreads();
        const bool narrow = (span_s <= 45);

        for (int t = 0; t < F; t++) {
            if ((t & 15) == 0 && t >= 16 && lane < WQ) {   // flush this wave's row
                int row = t - 16 + wvx;
                int c = lane, beat = c / TQ;
                float4 v4 = *(const float4*)&lring[((row & 31) << 8) + 4 * c + 4 * beat];
                *(float4*)&ws_lastv[(size_t)row * NP + 4 * c] = v4;
            }
            if (act_a) {
                const float* lvR = &lring[((t + 31) & 31) << 8];
                float mvv = -INFINITY;
                if (narrow) {
                    const float* rp = lvR + rowbase + c0;
                    #pragma unroll
                    for (int q = 0; q < BW2 / 4; q++) {
                        float4 l = *(const float4*)(rp + 4 * q);
                        mvv = fmaxf(mvv, fmaxf(fmaxf(l.x + ltb[4*q+0], l.y + ltb[4*q+1]),
                                               fmaxf(l.z + ltb[4*q+2], l.w + ltb[4*q+3])));
                    }
                } else {
                    for (int i = 0; i < T; i++) {
                        float ltv = isbf ? bf16u_to_f(lt_u[colbase + i * T]) : lt_f[colbase + i * T];
                        mvv = fmaxf(mvv, lvR[rowbase + i] + ltv);
                    }
                }
                bestp2[((t & 1) << 8) + b * T + j] = mvv + densr[((t & 63) << 2) + dsel];
            }
            __syncthreads();
        }
        if (lane == 0) { wvs[wvx] = -INFINITY; wss[wvx] = 0x7FFFFFFF; }
    } else {
        // ================= UPDATE WAVES (4..15) =================
        const int ut = tid - AOFF;
        const int uw = wvx - 4;
        const bool act_u = (ut < NT);
        int g_own = 0, startg = 0, Lg = 1, sb = 0, lq = 0, kk_head = -1;
        bool is_last = false, pv2 = false, pred_is_head = false;
        if (act_u) {
            int lo = 0, hi = NP - 1;
            while (lo < hi) { int mid = (lo + hi + 1) >> 1; if (pref[mid] <= ut) lo = mid; else hi = mid - 1; }
            g_own = lo;
            int j = ut - pref[lo];
            int b = g_own / T, ib = g_own - b * T;
            startg = fsld[g_own];
            int end = (ib + 1 < T) ? fsld[g_own + 1] : (b + 1) * nsb;
            Lg = end - startg;
            int n = (Lg + KF4 - 1) / KF4;
            sb = startg + Lg - KF4 * (n - j);
            is_last = (j == n - 1);
            lq = (b << 6) + ib;
            pv2 = (b == 0);
            int i0 = sb - startg;
            kk_head = (i0 <= 0) ? (-i0) : -1;
            pred_is_head = (i0 == 1);
        }
        bool hb[KF4], hpp[KF4];
        #pragma unroll
        for (int kk = 0; kk < KF4; kk++) {
            int i = (sb - startg) + kk;
            hb[kk]  = act_u && (16 * i < Lg);
            hpp[kk] = act_u && (kk >= 1) && (i == 1);
        }
        float vreg[KF4];
        #pragma unroll
        for (int kk = 0; kk < KF4; kk++) vreg[kk] = vinit;
        if (act_u && is_last) lring[(31 << 8) + lq] = vinit;   // t=0 reads slot 31
        if (lane == 63) bound2[16 + uw] = vinit;               // t=0 parity 1
        __syncthreads();

        for (int t = 0; t < F; t++) {
            if ((t & 15) == 0 && t >= 16 && lane < WQ) {       // flush duty
                int row = t - 16 + wvx;
                int c = lane, beat = c / TQ;
                float4 v4 = *(const float4*)&lring[((row & 31) << 8) + 4 * c + 4 * beat];
                *(float4*)&ws_lastv[(size_t)row * NP + 4 * c] = v4;
            }
            if (wvx == 14 && (t & 31) == 0 && t >= 32 && lane < 32) {  // dens refill
                int fr = t + 31 + lane;
                if (fr < F) {
                    float4 r = *(const float4*)&ws_dens[fr * 4];
                    *(float4*)&densr[(fr & 63) * 4] = r;
                }
            }
            float sh = __shfl_up(vreg[KF4 - 1], 1, 64);
            float patchv = bestp2[(((t + 1) & 1) << 8) + g_own];    // frame t-1 head value
            float4 dn = *(const float4*)&densr[(t & 63) << 2];
            float d0 = dn.x;
            float dpv = pv2 ? dn.z : dn.y;
            float inc = (lane == 0) ? bound2[(((t + 1) & 1) << 4) + ((uw + 15) & 15)] : sh;
            inc = pred_is_head ? patchv : inc;
            #pragma unroll
            for (int kk = KF4 - 1; kk >= 0; kk--) {
                float prev = (kk == 0) ? inc : vreg[kk - 1];
                prev = hpp[kk] ? patchv : prev;
                float add = hb[kk] ? dpv : d0;
                vreg[kk] = prev + add;               // bit-exact vs reference
            }
            if (act_u && is_last) lring[((t & 31) << 8) + lq] = vreg[KF4 - 1];
            if (lane == 63) bound2[((t & 1) << 4) + uw] = vreg[KF4 - 1];
            __syncthreads();
        }

        // final: inject pending head patch, wave-reduce
        float patchF = bestp2[(((F - 1) & 1) << 8) + g_own];
        float mv = -INFINITY; int ms = 0x7FFFFFFF;
        #pragma unroll
        for (int kk = 0; kk < KF4; kk++) {
            int s = sb + kk;
            float v = (kk == kk_head) ? patchF : vreg[kk];
            if (act_u && s >= startg && v > mv) { mv = v; ms = s; }
        }
        #pragma unroll
        for (int d = 1; d < 64; d <<= 1) {
            float ov = __shfl_xor(mv, d, 64);
            int   os = __shfl_xor(ms, d, 64);
            if (ov > mv || (ov == mv && os < ms)) { mv = ov; ms = os; }
        }
        if (lane == 0) { wvs[wvx] = mv; wss[wvx] = ms; }
    }

    // ---- tail flush rows [(F-1)&~15, F-2] (1 row per wave)
    __syncthreads();
    {
        int t0 = (F - 1) & ~15;
        int row = t0 + wvx;
        if (row <= F - 2 && lane < WQ) {
            int c = lane, beat = c / TQ;
            float4 v4 = *(const float4*)&lring[((row & 31) << 8) + 4 * c + 4 * beat];
            *(float4*)&ws_lastv[(size_t)row * NP + 4 * c] = v4;
        }
        __threadfence();
    }
    __syncthreads();

    if (tid == 0) {
        float bm = -INFINITY; int bs = 0x7FFFFFFF;
        for (int w = 0; w < 16; w++) {
            if (wvs[w] > bm || (wvs[w] == bm && wss[w] < bs)) { bm = wvs[w]; bs = wss[w]; }
        }
        int s = bs;
        int t = F - 1;
        out[F - 1] = (float)s;
        while (t > 0) {
            int b = s / nsb;
            int lo = b * T, hi = b * T + T - 1;
            while (lo < hi) { int mid = (lo + hi + 1) >> 1; if (fsld[mid] <= s) lo = mid; else hi = mid - 1; }
            int p = lo;
            int run = s - fsld[p];
            if (run == 0) {
                int jt = p - b * T;
                int pb = (b + 3) & 3;
                const float* lrow = &ws_lastv[(size_t)(t - 1) * NP + pb * T];
                float bmv = -INFINITY; int ai = 0;
                for (int i = 0; i < T; i++) {
                    int idx = (b * T + i) * T + jt;
                    float ltv = isbf ? bf16u_to_f(lt_u[idx]) : lt_f[idx];
                    float sc = lrow[i] + ltv;
                    if (sc > bmv) { bmv = sc; ai = i; }
                }
                s = plds[b * T + ai];
                out[t - 1] = (float)s;
                t--;
            } else {
                int m = (run < t) ? run : t;
                for (int jj = 0; jj < m; jj++) out[t - 1 - jj] = (float)(s - 1 - jj);
                s -= m; t -= m;
            }
        }
        out[F] = bm;   // logp
    }
}

// ============================ v2 kernel (round-9, proven fallback) ============================
template<int CTRL>
__device__ __forceinline__ int dpp_i(int x) {
    return __builtin_amdgcn_update_dpp(0, x, CTRL, 0xF, 0xF, true);
}
template<int CTRL>
__device__ __forceinline__ float dpp_f(float x) {
    return __int_as_float(dpp_i<CTRL>(__float_as_int(x)));
}

__global__ __launch_bounds__(1024) void dbn_viterbi_v2(
    const void* __restrict__ acts_raw, const void* __restrict__ lt_raw,
    const int* __restrict__ prev_last, const int* __restrict__ first_states,
    float* __restrict__ out, float* __restrict__ ws_lastv, float* __restrict__ ws_dens,
    int T, int S, int F)
{
    const int tid  = (int)threadIdx.x;
    const int NP   = NB * T;
    const int lane = tid & 63;
    const int wvx  = tid >> 6;

    __shared__ alignas(16) float lring[32 * 256];
    __shared__ alignas(16) float densr[64 * 4];
    __shared__ float bestv[NPMAX];
    __shared__ float bound[16];
    __shared__ int   fsld[NPMAX];
    __shared__ int   plds[NPMAX];
    __shared__ int   pref[NPMAX + 1];
    __shared__ float wvs[16];
    __shared__ int   wss[16];
    __shared__ int   flag_s, mspan_s;

    if (tid == 0) {
        const uint16_t* au = (const uint16_t*)acts_raw;
        int bf = 1;
        for (int i = 0; i < 32; i++) {
            uint16_t e = au[2 * i];
            uint8_t h8 = (uint8_t)(e >> 8);
            if (!(e == 0 || (h8 >= 0x20 && h8 < 0x40))) bf = 0;
        }
        flag_s = bf; mspan_s = 0;
    }
    if (tid < NP) { fsld[tid] = first_states[tid]; plds[tid] = prev_last[tid]; }
    for (int i = tid; i < 32 * 256; i += 1024) lring[i] = NEGV;
    __syncthreads();
    const int isbf = flag_s;
    const int nsb  = S / NB;
    const uint16_t* lt_u = (const uint16_t*)lt_raw;
    const float*    lt_f = (const float*)lt_raw;

    for (int f = tid; f < F; f += 1024) {
        float ab, ad;
        load_acts(acts_raw, isbf, f, ab, ad);
        float4 r;
        r.x = logf(((1.0f - ab) - ad) / 15.0f);
        r.y = logf(ab);
        r.z = logf(ad);
        r.w = 0.0f;
        *(float4*)&ws_dens[f * 4] = r;
    }
    __threadfence();
    if (tid == 0) {
        int acc = 0;
        for (int g = 0; g < NP; g++) {
            int b = g / T, ib = g - b * T;
            int end = (ib + 1 < T) ? fsld[g + 1] : (b + 1) * nsb;
            int L = end - fsld[g];
            pref[g] = acc; acc += (L + KF - 1) / KF;
        }
        pref[NP] = acc;
    }
    __syncthreads();
    const int NT = pref[NP];

    const bool act_u = (tid < NT);
    int g_own = 0, startg = 0, Lg = 1, sb = 0, lq = 0;
    bool is_last = false, pv2 = false;
    if (act_u) {
        int lo = 0, hi = NP - 1;
        while (lo < hi) { int mid = (lo + hi + 1) >> 1; if (pref[mid] <= tid) lo = mid; else hi = mid - 1; }
        g_own = lo;
        int j = tid - pref[lo];
        int b = g_own / T, ib = g_own - b * T;
        startg = fsld[g_own];
        int end = (ib + 1 < T) ? fsld[g_own + 1] : (b + 1) * nsb;
        Lg = end - startg;
        int n = (Lg + KF - 1) / KF;
        sb = startg + Lg - KF * (n - j);
        is_last = (j == n - 1);
        lq = (b << 6) + ib;
        pv2 = (b == 0);
    }
    bool hb[KF], hq[KF];
    #pragma unroll
    for (int kk = 0; kk < KF; kk++) {
        int i = sb + kk - startg;
        hq[kk] = act_u && (i <= 0);
        hb[kk] = act_u && (16 * i < Lg);
    }

    const int g_a = tid >> 2, k4 = tid & 3;
    const bool act_g = (g_a < NP);
    int rowbase = 0, lo_b = 0, b_a = 0, j_a = 0;
    if (act_g) {
        b_a = g_a / T; j_a = g_a - b_a * T;
        rowbase = ((b_a + 3) & 3) << 6;
        int lo = T, hi = 0;
        for (int i = 0; i < T; i++) {
            int idx = (b_a * T + i) * T + j_a;
            float v = isbf ? bf16u_to_f(lt_u[idx]) : lt_f[idx];
            if (v > -1e29f) { if (i < lo) lo = i; hi = i; }
        }
        lo_b = lo;
        if (k4 == 0) atomicMax(&mspan_s, hi - lo + 1);
    }
    __syncthreads();
    const bool banded = (mspan_s <= 44);
    float ltreg[QW];
    #pragma unroll
    for (int u = 0; u < QW; u++) ltreg[u] = NEGV;
    int cb = 0;
    if (act_g) {
        if (banded) { cb = (lo_b & ~3) + 12 * k4; if (cb > 52) cb = 52; }
        else cb = 16 * k4;
        const int nu = banded ? 12 : 16;
        for (int u = 0; u < nu; u++) {
            int i = cb + u;
            if (i < T) {
                int idx = (b_a * T + i) * T + j_a;
                ltreg[u] = isbf ? bf16u_to_f(lt_u[idx]) : lt_f[idx];
            }
        }
    }

    const float vinit = -logf((float)S);
    float vreg[KF];
    #pragma unroll
    for (int kk = 0; kk < KF; kk++) vreg[kk] = vinit;
    if (act_u && is_last) lring[(31 << 8) + lq] = vinit;
    if (lane == 63) bound[wvx] = vinit;
    float inc_pipe = vinit;
    if (tid < 64 && tid < F) {
        float4 r = *(const float4*)&ws_dens[tid * 4];
        *(float4*)&densr[tid * 4] = r;
    }
    const int WQ = NP >> 2, TQ = T >> 2;

    for (int t = 0; t < F; t++) {
        __syncthreads();
        const float* lvR = &lring[((t + 31) & 31) << 8];
        float inc_use = inc_pipe;
        if (lane == 0) inc_use = bound[(wvx + 15) & 15];

        if (wvx == 15) {
            if ((t & 31) == 0 && t >= 32 && lane < 32) {
                int fr = t + 32 + lane;
                if (fr < F) {
                    float4 r = *(const float4*)&ws_dens[fr * 4];
                    *(float4*)&densr[(fr & 63) * 4] = r;
                }
            }
            if ((t & 15) == 0 && t > 0 && lane < WQ) {
                int c = lane, beat = c / TQ;
                int srcoff = 4 * c + 4 * beat, t0 = t - 16;
                for (int r2 = 0; r2 < 16; r2++) {
                    int row = t0 + r2;
                    float4 v4 = *(const float4*)&lring[((row & 31) << 8) + srcoff];
                    *(float4*)&ws_lastv[(size_t)row * NP + 4 * c] = v4;
                }
            }
        } else if (act_g) {
            const float* rowp = lvR + rowbase + cb;
            float4 l0 = *(const float4*)(rowp + 0);
            float4 l1 = *(const float4*)(rowp + 4);
            float4 l2 = *(const float4*)(rowp + 8);
            float m0 = fmaxf(fmaxf(l0.x + ltreg[0], l0.y + ltreg[1]),
                             fmaxf(l0.z + ltreg[2], l0.w + ltreg[3]));
            float m1 = fmaxf(fmaxf(l1.x + ltreg[4], l1.y + ltreg[5]),
                             fmaxf(l1.z + ltreg[6], l1.w + ltreg[7]));
            float m2 = fmaxf(fmaxf(l2.x + ltreg[8], l2.y + ltreg[9]),
                             fmaxf(l2.z + ltreg[10], l2.w + ltreg[11]));
            float mv = fmaxf(fmaxf(m0, m1), m2);
            if (!banded) {
                float4 l3 = *(const float4*)(rowp + 12);
                float m3 = fmaxf(fmaxf(l3.x + ltreg[12], l3.y + ltreg[13]),
                                 fmaxf(l3.z + ltreg[14], l3.w + ltreg[15]));
                mv = fmaxf(mv, m3);
            }
            mv = fmaxf(mv, dpp_f<0xB1>(mv));
            mv = fmaxf(mv, dpp_f<0x4E>(mv));
            if (k4 == 0) bestv[g_a] = mv;
        }

        __syncthreads();
        int doff = (t & 63) << 2;
        float d0  = densr[doff];
        float dpv = densr[doff + (pv2 ? 2 : 1)];
        float bq  = bestv[g_own];
        #pragma unroll
        for (int kk = KF - 1; kk >= 0; kk--) {
            float prev = (kk == 0) ? inc_use : vreg[kk - 1];
            prev = hq[kk] ? bq : prev;
            float add = hb[kk] ? dpv : d0;
            vreg[kk] = prev + add;
        }
        if (act_u && is_last) lring[((t & 31) << 8) + lq] = vreg[KF - 1];
        if (lane == 63) bound[wvx] = vreg[KF - 1];
        inc_pipe = __shfl_up(vreg[KF - 1], 1, 64);
    }

    __syncthreads();
    if (wvx == 15 && lane < WQ) {
        int lastf = (F - 1) & ~15;
        int c = lane, beat = c / TQ;
        int srcoff = 4 * c + 4 * beat;
        for (int row = lastf; row <= F - 2; row++) {
            float4 v4 = *(const float4*)&lring[((row & 31) << 8) + srcoff];
            *(float4*)&ws_lastv[(size_t)row * NP + 4 * c] = v4;
        }
        __threadfence();
    }

    float mv = -INFINITY; int ms = 0x7FFFFFFF;
    #pragma unroll
    for (int kk = 0; kk < KF; kk++) {
        int s = sb + kk;
        bool valid = act_u && (s >= startg);
        float v = vreg[kk];
        if (valid && v > mv) { mv = v; ms = s; }
    }
    #pragma unroll
    for (int d = 1; d < 64; d <<= 1) {
        float ov = __shfl_xor(mv, d, 64);
        int   os = __shfl_xor(ms, d, 64);
        if (ov > mv || (ov == mv && os < ms)) { mv = ov; ms = os; }
    }
    if (lane == 0) { wvs[wvx] = mv; wss[wvx] = ms; }
    __syncthreads();

    if (tid == 0) {
        float bm = -INFINITY; int bs = 0x7FFFFFFF;
        for (int w = 0; w < 16; w++) {
            if (wvs[w] > bm || (wvs[w] == bm && wss[w] < bs)) { bm = wvs[w]; bs = wss[w]; }
        }
        int s = bs;
        int t = F - 1;
        out[F - 1] = (float)s;
        while (t > 0) {
            int b = s / nsb;
            int lo = b * T, hi = b * T + T - 1;
            while (lo < hi) { int mid = (lo + hi + 1) >> 1; if (fsld[mid] <= s) lo = mid; else hi = mid - 1; }
            int p = lo;
            int run = s - fsld[p];
            if (run == 0) {
                int jt = p - b * T;
                int pb = (b + 3) & 3;
                const float* lrow = &ws_lastv[(size_t)(t - 1) * NP + pb * T];
                float bmv = -INFINITY; int ai = 0;
                for (int i = 0; i < T; i++) {
                    int idx = (b * T + i) * T + jt;
                    float ltv = isbf ? bf16u_to_f(lt_u[idx]) : lt_f[idx];
                    float sc = lrow[i] + ltv;
                    if (sc > bmv) { bmv = sc; ai = i; }
                }
                s = plds[b * T + ai];
                out[t - 1] = (float)s;
                t--;
            } else {
                int m = (run < t) ? run : t;
                for (int jj = 0; jj < m; jj++) out[t - 1 - jj] = (float)(s - 1 - jj);
                s -= m; t -= m;
            }
        }
        out[F] = bm;
    }
}

extern "C" void kernel_launch(void* const* d_in, const int* in_sizes, int n_in,
                              void* d_out, int out_size, void* d_ws, size_t ws_size,
                              hipStream_t stream) {
    const int F  = in_sizes[0] / 2;     // frames
    const int NP = in_sizes[2];         // NB*T
    const int T  = NP / NB;             // tempi
    const int S  = in_sizes[4];         // total states

    const size_t need = ((size_t)F * NP + 4 * (size_t)F) * 4;
    float* ws_lv = (float*)d_ws;
    float* ws_de = ws_lv + (size_t)F * NP;

    const bool base = ((T & 3) == 0) && (T <= 64) && (NP <= NPMAX) && (F >= 2)
                   && ((S % NB) == 0) && (ws_size >= need);
    // v4: 12 update waves suffice for any block-length split iff S/32 + NP <= 768
    const bool okv4 = base && (S <= KF4 * (768 - NP));
    const bool okv2 = base && (S <= KF * 1024);

    if (okv4) {
        hipLaunchKernelGGL(dbn_viterbi_v4, dim3(1), dim3(1024), 0, stream,
                           d_in[0], d_in[1],
                           (const int*)d_in[2], (const int*)d_in[3],
                           (float*)d_out, ws_lv, ws_de, T, S, F);
    } else if (okv2) {
        hipLaunchKernelGGL(dbn_viterbi_v2, dim3(1), dim3(1024), 0, stream,
                           d_in[0], d_in[1],
                           (const int*)d_in[2], (const int*)d_in[3],
                           (float*)d_out, ws_lv, ws_de, T, S, F);
    }
}

// Round 13
// 6093.011 us; speedup vs baseline: 1.4198x; 1.4198x over previous
//
#include <hip/hip_runtime.h>
#include <stdint.h>

// DBN downbeat Viterbi, single persistent 1024-thread workgroup, v in REGISTERS.
// v5: ONE barrier/frame, fused roles (v2 costs + v4 deferred-head-patch).
//   Every thread: (a) 4-lane banded argmax for group g_a over lring[(t-1)&31],
//   stores bestp2[t&1] = max + dens_t (pre-added head value, never enters vreg);
//   (b) KF=15 register-shift update consuming bestp2[(t-1)&1] as the i==1 patch
//   (hpp mask / pred_is_head seam / final kk_head injection).
//   argmax(t) and update(t) are independent -> single barrier, no added work.
//   dens precomputed to ws, 64-slot ring (refill [t+31,t+62] per 32 frames);
//   lastv history in 32-slot lring, 1 row/wave flushed every 16 frames.
// v2 fallback = round-9 proven kernel. Output: float32 (path+logp). Bit-exact.

#define NB 4
#define KF 15
#define QW 16
#define NPMAX 256
#define NEGV -1.0e30f

__device__ __forceinline__ float bf16u_to_f(uint16_t u) {
    union { uint32_t i; float f; } v; v.i = ((uint32_t)u) << 16; return v.f;
}
template<int CTRL>
__device__ __forceinline__ int dpp_i(int x) {
    return __builtin_amdgcn_update_dpp(0, x, CTRL, 0xF, 0xF, true);
}
template<int CTRL>
__device__ __forceinline__ float dpp_f(float x) {
    return __int_as_float(dpp_i<CTRL>(__float_as_int(x)));
}
__device__ __forceinline__ void load_acts(const void* p, int isbf, int t, float& a, float& d) {
    if (isbf) {
        const uint16_t* u = (const uint16_t*)p;
        uint32_t w = *(const uint32_t*)(u + 2 * t);
        a = bf16u_to_f((uint16_t)w); d = bf16u_to_f((uint16_t)(w >> 16));
    } else {
        const float2* f = (const float2*)p;
        float2 v = f[t]; a = v.x; d = v.y;
    }
}

// ============================ v5 kernel ============================
__global__ __launch_bounds__(1024) void dbn_viterbi_v5(
    const void* __restrict__ acts_raw,     // F*2, f32 or bf16 (detected)
    const void* __restrict__ lt_raw,       // NB*T*T, f32 or bf16
    const int*  __restrict__ prev_last,    // NB*T
    const int*  __restrict__ first_states, // NB*T
    float*      __restrict__ out,          // F+1 float32
    float*      __restrict__ ws_lastv,     // F*NP floats
    float*      __restrict__ ws_dens,      // F*4 floats
    int T, int S, int F)
{
    const int tid  = (int)threadIdx.x;
    const int NP   = NB * T;
    const int lane = tid & 63;
    const int wvx  = tid >> 6;

    __shared__ alignas(16) float lring[32 * 256];  // lastv ring [slot][beat<<6|i]
    __shared__ alignas(16) float densr[64 * 4];    // dens ring
    __shared__ float bestp2[2 * 256];              // [parity][g]: head value (max+dens)
    __shared__ float bound2[32];                   // [parity][wave]
    __shared__ int   fsld[NPMAX];
    __shared__ int   plds[NPMAX];
    __shared__ int   pref[NPMAX + 1];
    __shared__ float wvs[16];
    __shared__ int   wss[16];
    __shared__ int   flag_s, mspan_s;

    // ---- dtype detection (bf16 exponent bytes in [0x20,0x40))
    if (tid == 0) {
        const uint16_t* au = (const uint16_t*)acts_raw;
        int bf = 1;
        for (int i = 0; i < 32; i++) {
            uint16_t e = au[2 * i];
            uint8_t h8 = (uint8_t)(e >> 8);
            if (!(e == 0 || (h8 >= 0x20 && h8 < 0x40))) bf = 0;
        }
        flag_s = bf; mspan_s = 0;
    }
    if (tid < NP) { fsld[tid] = first_states[tid]; plds[tid] = prev_last[tid]; }
    for (int i = tid; i < 32 * 256; i += 1024) lring[i] = NEGV;
    __syncthreads();
    const int isbf = flag_s;
    const int nsb  = S / NB;
    const uint16_t* lt_u = (const uint16_t*)lt_raw;
    const float*    lt_f = (const float*)lt_raw;

    // ---- dens precompute (all frames) into ws_dens
    for (int f = tid; f < F; f += 1024) {
        float ab, ad;
        load_acts(acts_raw, isbf, f, ab, ad);
        float4 r;
        r.x = logf(((1.0f - ab) - ad) / 15.0f);
        r.y = logf(ab);
        r.z = logf(ad);
        r.w = 0.0f;
        *(float4*)&ws_dens[f * 4] = r;
    }
    __threadfence();
    if (tid == 0) {
        int acc = 0;
        for (int g = 0; g < NP; g++) {
            int b = g / T, ib = g - b * T;
            int end = (ib + 1 < T) ? fsld[g + 1] : (b + 1) * nsb;
            int L = end - fsld[g];
            pref[g] = acc; acc += (L + KF - 1) / KF;
        }
        pref[NP] = acc;
    }
    __syncthreads();
    const int NT = pref[NP];
    const float vinit = -logf((float)S);
    const int WQ = NP >> 2, TQ = T >> 2;

    // ---- update-side assignment (end-aligned; head value NEVER stored)
    const bool act_u = (tid < NT);
    int g_own = 0, startg = 0, Lg = 1, sb = 0, lq = 0, kk_head = -1;
    bool is_last = false, pv2 = false, pred_is_head = false;
    if (act_u) {
        int lo = 0, hi = NP - 1;
        while (lo < hi) { int mid = (lo + hi + 1) >> 1; if (pref[mid] <= tid) lo = mid; else hi = mid - 1; }
        g_own = lo;
        int j = tid - pref[lo];
        int b = g_own / T, ib = g_own - b * T;
        startg = fsld[g_own];
        int end = (ib + 1 < T) ? fsld[g_own + 1] : (b + 1) * nsb;
        Lg = end - startg;
        int n = (Lg + KF - 1) / KF;
        sb = startg + Lg - KF * (n - j);
        is_last = (j == n - 1);
        lq = (b << 6) + ib;
        pv2 = (b == 0);
        int i0 = sb - startg;
        kk_head = (i0 <= 0) ? (-i0) : -1;
        pred_is_head = (i0 == 1);
    }
    bool hb[KF], hpp[KF];
    #pragma unroll
    for (int kk = 0; kk < KF; kk++) {
        int i = (sb - startg) + kk;
        hb[kk]  = act_u && (16 * i < Lg);
        hpp[kk] = act_u && (kk >= 1) && (i == 1);
    }

    // ---- argmax-side setup (4 lanes per group, banded)
    const int g_a = tid >> 2, k4 = tid & 3;
    const bool act_g = (g_a < NP);
    int rowbase = 0, lo_b = 0, b_a = 0, j_a = 0, dsel_a = 1;
    if (act_g) {
        b_a = g_a / T; j_a = g_a - b_a * T;
        rowbase = ((b_a + 3) & 3) << 6;
        dsel_a = (b_a == 0) ? 2 : 1;
        int lo = T, hi = 0;
        for (int i = 0; i < T; i++) {
            int idx = (b_a * T + i) * T + j_a;
            float v = isbf ? bf16u_to_f(lt_u[idx]) : lt_f[idx];
            if (v > -1e29f) { if (i < lo) lo = i; hi = i; }
        }
        lo_b = lo;
        if (k4 == 0) atomicMax(&mspan_s, hi - lo + 1);
    }
    __syncthreads();
    const bool banded = (mspan_s <= 44);
    float ltreg[QW];
    #pragma unroll
    for (int u = 0; u < QW; u++) ltreg[u] = NEGV;
    int cb = 0;
    if (act_g) {
        if (banded) { cb = (lo_b & ~3) + 12 * k4; if (cb > 52) cb = 52; }
        else cb = 16 * k4;
        const int nu = banded ? 12 : 16;
        for (int u = 0; u < nu; u++) {
            int i = cb + u;
            if (i < T) {
                int idx = (b_a * T + i) * T + j_a;
                ltreg[u] = isbf ? bf16u_to_f(lt_u[idx]) : lt_f[idx];
            }
        }
    }

    // ---- init
    float vreg[KF];
    #pragma unroll
    for (int kk = 0; kk < KF; kk++) vreg[kk] = vinit;
    if (act_u && is_last) lring[(31 << 8) + lq] = vinit;   // t=0 reads slot 31
    if (lane == 63) bound2[16 + wvx] = vinit;              // t=0 reads parity 1
    if (tid < 256) bestp2[256 + tid] = vinit;              // h(-1) = vinit
    if (tid < 64 && tid < F) {
        float4 r = *(const float4*)&ws_dens[tid * 4];
        *(float4*)&densr[tid * 4] = r;
    }
    __syncthreads();

    // ---- main loop: ONE barrier per frame
    for (int t = 0; t < F; t++) {
        // duties (amortized)
        if ((t & 15) == 0 && t >= 16 && lane < WQ) {           // flush row t-16+wvx
            int row = t - 16 + wvx;
            int c = lane, beat = c / TQ;
            float4 v4 = *(const float4*)&lring[((row & 31) << 8) + 4 * c + 4 * beat];
            *(float4*)&ws_lastv[(size_t)row * NP + 4 * c] = v4;
        }
        if (wvx == 15 && (t & 31) == 0 && t >= 32 && lane < 32) {  // dens refill
            int fr = t + 31 + lane;
            if (fr < F) {
                float4 r = *(const float4*)&ws_dens[fr * 4];
                *(float4*)&densr[(fr & 63) * 4] = r;
            }
        }

        // argmax role: head value h(t) from lastv(t-1), stored for frame t+1
        if (act_g) {
            const float* rowp = &lring[(((t + 31) & 31) << 8) + rowbase + cb];
            float4 l0 = *(const float4*)(rowp + 0);
            float4 l1 = *(const float4*)(rowp + 4);
            float4 l2 = *(const float4*)(rowp + 8);
            float m0 = fmaxf(fmaxf(l0.x + ltreg[0], l0.y + ltreg[1]),
                             fmaxf(l0.z + ltreg[2], l0.w + ltreg[3]));
            float m1 = fmaxf(fmaxf(l1.x + ltreg[4], l1.y + ltreg[5]),
                             fmaxf(l1.z + ltreg[6], l1.w + ltreg[7]));
            float m2 = fmaxf(fmaxf(l2.x + ltreg[8], l2.y + ltreg[9]),
                             fmaxf(l2.z + ltreg[10], l2.w + ltreg[11]));
            float mv = fmaxf(fmaxf(m0, m1), m2);
            if (!banded) {
                float4 l3 = *(const float4*)(rowp + 12);
                float m3 = fmaxf(fmaxf(l3.x + ltreg[12], l3.y + ltreg[13]),
                                 fmaxf(l3.z + ltreg[14], l3.w + ltreg[15]));
                mv = fmaxf(mv, m3);
            }
            mv = fmaxf(mv, dpp_f<0xB1>(mv));
            mv = fmaxf(mv, dpp_f<0x4E>(mv));
            if (k4 == 0) bestp2[((t & 1) << 8) + g_a] = mv + densr[((t & 63) << 2) + dsel_a];
        }

        // update role: consumes h(t-1) = bestp2[(t-1)&1] as the i==1 patch
        float sh = __shfl_up(vreg[KF - 1], 1, 64);
        float patchv = bestp2[(((t + 1) & 1) << 8) + g_own];
        int doff = (t & 63) << 2;
        float d0  = densr[doff];
        float dpv = densr[doff + (pv2 ? 2 : 1)];
        float inc = (lane == 0) ? bound2[(((t + 1) & 1) << 4) + ((wvx + 15) & 15)] : sh;
        inc = pred_is_head ? patchv : inc;
        #pragma unroll
        for (int kk = KF - 1; kk >= 0; kk--) {
            float prev = (kk == 0) ? inc : vreg[kk - 1];
            prev = hpp[kk] ? patchv : prev;
            float add = hb[kk] ? dpv : d0;
            vreg[kk] = prev + add;               // bit-exact vs reference
        }
        if (act_u && is_last) lring[((t & 31) << 8) + lq] = vreg[KF - 1];
        if (lane == 63) bound2[((t & 1) << 4) + wvx] = vreg[KF - 1];

        __syncthreads();   // frame t fully visible
    }

    // ---- tail flush rows [(F-1)&~15, F-2] (1 row per wave)
    {
        int t0 = (F - 1) & ~15;
        int row = t0 + wvx;
        if (row <= F - 2 && lane < WQ) {
            int c = lane, beat = c / TQ;
            float4 v4 = *(const float4*)&lring[((row & 31) << 8) + 4 * c + 4 * beat];
            *(float4*)&ws_lastv[(size_t)row * NP + 4 * c] = v4;
        }
        __threadfence();
    }

    // ---- final argmax (inject pending head patch at kk_head)
    float patchF = bestp2[(((F - 1) & 1) << 8) + g_own];
    float mv = -INFINITY; int ms = 0x7FFFFFFF;
    #pragma unroll
    for (int kk = 0; kk < KF; kk++) {
        int s = sb + kk;
        float v = (kk == kk_head) ? patchF : vreg[kk];
        if (act_u && s >= startg && v > mv) { mv = v; ms = s; }
    }
    #pragma unroll
    for (int d = 1; d < 64; d <<= 1) {
        float ov = __shfl_xor(mv, d, 64);
        int   os = __shfl_xor(ms, d, 64);
        if (ov > mv || (ov == mv && os < ms)) { mv = ov; ms = os; }
    }
    if (lane == 0) { wvs[wvx] = mv; wss[wvx] = ms; }
    __syncthreads();

    if (tid == 0) {
        float bm = -INFINITY; int bs = 0x7FFFFFFF;
        for (int w = 0; w < 16; w++) {
            if (wvs[w] > bm || (wvs[w] == bm && wss[w] < bs)) { bm = wvs[w]; bs = wss[w]; }
        }
        int s = bs;
        int t = F - 1;
        out[F - 1] = (float)s;
        while (t > 0) {
            int b = s / nsb;
            int lo = b * T, hi = b * T + T - 1;
            while (lo < hi) { int mid = (lo + hi + 1) >> 1; if (fsld[mid] <= s) lo = mid; else hi = mid - 1; }
            int p = lo;
            int run = s - fsld[p];
            if (run == 0) {
                int jt = p - b * T;
                int pb = (b + 3) & 3;
                const float* lrow = &ws_lastv[(size_t)(t - 1) * NP + pb * T];
                float bmv = -INFINITY; int ai = 0;
                for (int i = 0; i < T; i++) {
                    int idx = (b * T + i) * T + jt;
                    float ltv = isbf ? bf16u_to_f(lt_u[idx]) : lt_f[idx];
                    float sc = lrow[i] + ltv;
                    if (sc > bmv) { bmv = sc; ai = i; }
                }
                s = plds[b * T + ai];
                out[t - 1] = (float)s;
                t--;
            } else {
                int m = (run < t) ? run : t;
                for (int jj = 0; jj < m; jj++) out[t - 1 - jj] = (float)(s - 1 - jj);
                s -= m; t -= m;
            }
        }
        out[F] = bm;   // logp
    }
}

// ============================ v2 kernel (round-9, proven fallback) ============================
__global__ __launch_bounds__(1024) void dbn_viterbi_v2(
    const void* __restrict__ acts_raw, const void* __restrict__ lt_raw,
    const int* __restrict__ prev_last, const int* __restrict__ first_states,
    float* __restrict__ out, float* __restrict__ ws_lastv, float* __restrict__ ws_dens,
    int T, int S, int F)
{
    const int tid  = (int)threadIdx.x;
    const int NP   = NB * T;
    const int lane = tid & 63;
    const int wvx  = tid >> 6;

    __shared__ alignas(16) float lring[32 * 256];
    __shared__ alignas(16) float densr[64 * 4];
    __shared__ float bestv[NPMAX];
    __shared__ float bound[16];
    __shared__ int   fsld[NPMAX];
    __shared__ int   plds[NPMAX];
    __shared__ int   pref[NPMAX + 1];
    __shared__ float wvs[16];
    __shared__ int   wss[16];
    __shared__ int   flag_s, mspan_s;

    if (tid == 0) {
        const uint16_t* au = (const uint16_t*)acts_raw;
        int bf = 1;
        for (int i = 0; i < 32; i++) {
            uint16_t e = au[2 * i];
            uint8_t h8 = (uint8_t)(e >> 8);
            if (!(e == 0 || (h8 >= 0x20 && h8 < 0x40))) bf = 0;
        }
        flag_s = bf; mspan_s = 0;
    }
    if (tid < NP) { fsld[tid] = first_states[tid]; plds[tid] = prev_last[tid]; }
    for (int i = tid; i < 32 * 256; i += 1024) lring[i] = NEGV;
    __syncthreads();
    const int isbf = flag_s;
    const int nsb  = S / NB;
    const uint16_t* lt_u = (const uint16_t*)lt_raw;
    const float*    lt_f = (const float*)lt_raw;

    for (int f = tid; f < F; f += 1024) {
        float ab, ad;
        load_acts(acts_raw, isbf, f, ab, ad);
        float4 r;
        r.x = logf(((1.0f - ab) - ad) / 15.0f);
        r.y = logf(ab);
        r.z = logf(ad);
        r.w = 0.0f;
        *(float4*)&ws_dens[f * 4] = r;
    }
    __threadfence();
    if (tid == 0) {
        int acc = 0;
        for (int g = 0; g < NP; g++) {
            int b = g / T, ib = g - b * T;
            int end = (ib + 1 < T) ? fsld[g + 1] : (b + 1) * nsb;
            int L = end - fsld[g];
            pref[g] = acc; acc += (L + KF - 1) / KF;
        }
        pref[NP] = acc;
    }
    __syncthreads();
    const int NT = pref[NP];

    const bool act_u = (tid < NT);
    int g_own = 0, startg = 0, Lg = 1, sb = 0, lq = 0;
    bool is_last = false, pv2 = false;
    if (act_u) {
        int lo = 0, hi = NP - 1;
        while (lo < hi) { int mid = (lo + hi + 1) >> 1; if (pref[mid] <= tid) lo = mid; else hi = mid - 1; }
        g_own = lo;
        int j = tid - pref[lo];
        int b = g_own / T, ib = g_own - b * T;
        startg = fsld[g_own];
        int end = (ib + 1 < T) ? fsld[g_own + 1] : (b + 1) * nsb;
        Lg = end - startg;
        int n = (Lg + KF - 1) / KF;
        sb = startg + Lg - KF * (n - j);
        is_last = (j == n - 1);
        lq = (b << 6) + ib;
        pv2 = (b == 0);
    }
    bool hb[KF], hq[KF];
    #pragma unroll
    for (int kk = 0; kk < KF; kk++) {
        int i = sb + kk - startg;
        hq[kk] = act_u && (i <= 0);
        hb[kk] = act_u && (16 * i < Lg);
    }

    const int g_a = tid >> 2, k4 = tid & 3;
    const bool act_g = (g_a < NP);
    int rowbase = 0, lo_b = 0, b_a = 0, j_a = 0;
    if (act_g) {
        b_a = g_a / T; j_a = g_a - b_a * T;
        rowbase = ((b_a + 3) & 3) << 6;
        int lo = T, hi = 0;
        for (int i = 0; i < T; i++) {
            int idx = (b_a * T + i) * T + j_a;
            float v = isbf ? bf16u_to_f(lt_u[idx]) : lt_f[idx];
            if (v > -1e29f) { if (i < lo) lo = i; hi = i; }
        }
        lo_b = lo;
        if (k4 == 0) atomicMax(&mspan_s, hi - lo + 1);
    }
    __syncthreads();
    const bool banded = (mspan_s <= 44);
    float ltreg[QW];
    #pragma unroll
    for (int u = 0; u < QW; u++) ltreg[u] = NEGV;
    int cb = 0;
    if (act_g) {
        if (banded) { cb = (lo_b & ~3) + 12 * k4; if (cb > 52) cb = 52; }
        else cb = 16 * k4;
        const int nu = banded ? 12 : 16;
        for (int u = 0; u < nu; u++) {
            int i = cb + u;
            if (i < T) {
                int idx = (b_a * T + i) * T + j_a;
                ltreg[u] = isbf ? bf16u_to_f(lt_u[idx]) : lt_f[idx];
            }
        }
    }

    const float vinit = -logf((float)S);
    float vreg[KF];
    #pragma unroll
    for (int kk = 0; kk < KF; kk++) vreg[kk] = vinit;
    if (act_u && is_last) lring[(31 << 8) + lq] = vinit;
    if (lane == 63) bound[wvx] = vinit;
    float inc_pipe = vinit;
    if (tid < 64 && tid < F) {
        float4 r = *(const float4*)&ws_dens[tid * 4];
        *(float4*)&densr[tid * 4] = r;
    }
    const int WQ = NP >> 2, TQ = T >> 2;

    for (int t = 0; t < F; t++) {
        __syncthreads();
        const float* lvR = &lring[((t + 31) & 31) << 8];
        float inc_use = inc_pipe;
        if (lane == 0) inc_use = bound[(wvx + 15) & 15];

        if (wvx == 15) {
            if ((t & 31) == 0 && t >= 32 && lane < 32) {
                int fr = t + 32 + lane;
                if (fr < F) {
                    float4 r = *(const float4*)&ws_dens[fr * 4];
                    *(float4*)&densr[(fr & 63) * 4] = r;
                }
            }
            if ((t & 15) == 0 && t > 0 && lane < WQ) {
                int c = lane, beat = c / TQ;
                int srcoff = 4 * c + 4 * beat, t0 = t - 16;
                for (int r2 = 0; r2 < 16; r2++) {
                    int row = t0 + r2;
                    float4 v4 = *(const float4*)&lring[((row & 31) << 8) + srcoff];
                    *(float4*)&ws_lastv[(size_t)row * NP + 4 * c] = v4;
                }
            }
        } else if (act_g) {
            const float* rowp = lvR + rowbase + cb;
            float4 l0 = *(const float4*)(rowp + 0);
            float4 l1 = *(const float4*)(rowp + 4);
            float4 l2 = *(const float4*)(rowp + 8);
            float m0 = fmaxf(fmaxf(l0.x + ltreg[0], l0.y + ltreg[1]),
                             fmaxf(l0.z + ltreg[2], l0.w + ltreg[3]));
            float m1 = fmaxf(fmaxf(l1.x + ltreg[4], l1.y + ltreg[5]),
                             fmaxf(l1.z + ltreg[6], l1.w + ltreg[7]));
            float m2 = fmaxf(fmaxf(l2.x + ltreg[8], l2.y + ltreg[9]),
                             fmaxf(l2.z + ltreg[10], l2.w + ltreg[11]));
            float mv = fmaxf(fmaxf(m0, m1), m2);
            if (!banded) {
                float4 l3 = *(const float4*)(rowp + 12);
                float m3 = fmaxf(fmaxf(l3.x + ltreg[12], l3.y + ltreg[13]),
                                 fmaxf(l3.z + ltreg[14], l3.w + ltreg[15]));
                mv = fmaxf(mv, m3);
            }
            mv = fmaxf(mv, dpp_f<0xB1>(mv));
            mv = fmaxf(mv, dpp_f<0x4E>(mv));
            if (k4 == 0) bestv[g_a] = mv;
        }

        __syncthreads();
        int doff = (t & 63) << 2;
        float d0  = densr[doff];
        float dpv = densr[doff + (pv2 ? 2 : 1)];
        float bq  = bestv[g_own];
        #pragma unroll
        for (int kk = KF - 1; kk >= 0; kk--) {
            float prev = (kk == 0) ? inc_use : vreg[kk - 1];
            prev = hq[kk] ? bq : prev;
            float add = hb[kk] ? dpv : d0;
            vreg[kk] = prev + add;
        }
        if (act_u && is_last) lring[((t & 31) << 8) + lq] = vreg[KF - 1];
        if (lane == 63) bound[wvx] = vreg[KF - 1];
        inc_pipe = __shfl_up(vreg[KF - 1], 1, 64);
    }

    __syncthreads();
    if (wvx == 15 && lane < WQ) {
        int lastf = (F - 1) & ~15;
        int c = lane, beat = c / TQ;
        int srcoff = 4 * c + 4 * beat;
        for (int row = lastf; row <= F - 2; row++) {
            float4 v4 = *(const float4*)&lring[((row & 31) << 8) + srcoff];
            *(float4*)&ws_lastv[(size_t)row * NP + 4 * c] = v4;
        }
        __threadfence();
    }

    float mv = -INFINITY; int ms = 0x7FFFFFFF;
    #pragma unroll
    for (int kk = 0; kk < KF; kk++) {
        int s = sb + kk;
        bool valid = act_u && (s >= startg);
        float v = vreg[kk];
        if (valid && v > mv) { mv = v; ms = s; }
    }
    #pragma unroll
    for (int d = 1; d < 64; d <<= 1) {
        float ov = __shfl_xor(mv, d, 64);
        int   os = __shfl_xor(ms, d, 64);
        if (ov > mv || (ov == mv && os < ms)) { mv = ov; ms = os; }
    }
    if (lane == 0) { wvs[wvx] = mv; wss[wvx] = ms; }
    __syncthreads();

    if (tid == 0) {
        float bm = -INFINITY; int bs = 0x7FFFFFFF;
        for (int w = 0; w < 16; w++) {
            if (wvs[w] > bm || (wvs[w] == bm && wss[w] < bs)) { bm = wvs[w]; bs = wss[w]; }
        }
        int s = bs;
        int t = F - 1;
        out[F - 1] = (float)s;
        while (t > 0) {
            int b = s / nsb;
            int lo = b * T, hi = b * T + T - 1;
            while (lo < hi) { int mid = (lo + hi + 1) >> 1; if (fsld[mid] <= s) lo = mid; else hi = mid - 1; }
            int p = lo;
            int run = s - fsld[p];
            if (run == 0) {
                int jt = p - b * T;
                int pb = (b + 3) & 3;
                const float* lrow = &ws_lastv[(size_t)(t - 1) * NP + pb * T];
                float bmv = -INFINITY; int ai = 0;
                for (int i = 0; i < T; i++) {
                    int idx = (b * T + i) * T + jt;
                    float ltv = isbf ? bf16u_to_f(lt_u[idx]) : lt_f[idx];
                    float sc = lrow[i] + ltv;
                    if (sc > bmv) { bmv = sc; ai = i; }
                }
                s = plds[b * T + ai];
                out[t - 1] = (float)s;
                t--;
            } else {
                int m = (run < t) ? run : t;
                for (int jj = 0; jj < m; jj++) out[t - 1 - jj] = (float)(s - 1 - jj);
                s -= m; t -= m;
            }
        }
        out[F] = bm;
    }
}

extern "C" void kernel_launch(void* const* d_in, const int* in_sizes, int n_in,
                              void* d_out, int out_size, void* d_ws, size_t ws_size,
                              hipStream_t stream) {
    const int F  = in_sizes[0] / 2;     // frames
    const int NP = in_sizes[2];         // NB*T
    const int T  = NP / NB;             // tempi
    const int S  = in_sizes[4];         // total states

    const size_t need = ((size_t)F * NP + 4 * (size_t)F) * 4;
    float* ws_lv = (float*)d_ws;
    float* ws_de = ws_lv + (size_t)F * NP;

    const bool base = ((T & 3) == 0) && (T <= 64) && (NP <= NPMAX) && (F >= 2)
                   && ((S % NB) == 0) && (S <= KF * 1024) && (ws_size >= need);

    if (base) {
        hipLaunchKernelGGL(dbn_viterbi_v5, dim3(1), dim3(1024), 0, stream,
                           d_in[0], d_in[1],
                           (const int*)d_in[2], (const int*)d_in[3],
                           (float*)d_out, ws_lv, ws_de, T, S, F);
    } else {
        hipLaunchKernelGGL(dbn_viterbi_v2, dim3(1), dim3(1024), 0, stream,
                           d_in[0], d_in[1],
                           (const int*)d_in[2], (const int*)d_in[3],
                           (float*)d_out, ws_lv, ws_de, T, S, F);
    }
}